// Round 16
// baseline (267.151 us; speedup 1.0000x reference)
//
#include <hip/hip_runtime.h>

#define EPSB 1e-5f

typedef __bf16 bf16x8 __attribute__((ext_vector_type(8)));
typedef float f32x4 __attribute__((ext_vector_type(4)));
typedef float f32x16 __attribute__((ext_vector_type(16)));

__device__ __forceinline__ unsigned short bfc(float v) {
  __bf16 h = (__bf16)v;
  return __builtin_bit_cast(unsigned short, h);
}
__device__ __forceinline__ unsigned int pk2(float a, float b) {
  return (unsigned int)bfc(a) | ((unsigned int)bfc(b) << 16);
}
__device__ __forceinline__ float sigm(float x) {
  float e = __builtin_amdgcn_exp2f(-x * 1.4426950408889634f);
  return __builtin_amdgcn_rcpf(1.0f + e);
}

// ---------------- prep: fold BN into bf16 weights ----------------
// wAe: [576][160] bf16, rows PERMUTED row' = kk*64+cc (o = cc*9+kk); k=147 bias slot
// w1e: [64][576] bf16, k permuted k' = kk*64+cc ; w2e: [64][576] kk-major
__global__ void prep_kernel(
    const float* __restrict__ w_att, const float* __restrict__ b_att,
    const float* __restrict__ gA, const float* __restrict__ beA,
    const float* __restrict__ mA, const float* __restrict__ vA,
    const float* __restrict__ w1, const float* __restrict__ b1,
    const float* __restrict__ g1, const float* __restrict__ be1,
    const float* __restrict__ m1, const float* __restrict__ v1,
    const float* __restrict__ w2, const float* __restrict__ b2,
    const float* __restrict__ g2, const float* __restrict__ be2,
    const float* __restrict__ m2, const float* __restrict__ v2,
    unsigned short* __restrict__ wAe, unsigned short* __restrict__ w1e,
    unsigned short* __restrict__ w2e, float* __restrict__ bias1,
    float* __restrict__ bias2)
{
  int i = blockIdx.x * 256 + threadIdx.x;
  if (i < 576 * 160) {
    int rp = i / 160, k = i - rp * 160;
    int kk = rp >> 6, cc = rp & 63;
    int o = cc * 9 + kk;
    float s = gA[o] * rsqrtf(vA[o] + EPSB);
    float v = 0.f;
    if (k < 147) {
      int c = k / 49, rem = k - c * 49, ki = rem / 7, kj = rem - ki * 7;
      v = w_att[(o * 3 + c) * 49 + ki * 7 + kj] * s;
    } else if (k == 147) {
      v = b_att[o] * s + beA[o] - mA[o] * s;
    }
    wAe[i] = bfc(v);
    return;
  }
  i -= 576 * 160;
  if (i < 64 * 576) {
    int o = i / 576, kp = i - o * 576;
    int kk = kp >> 6, cc = kp & 63;
    float s = g1[o] * rsqrtf(v1[o] + EPSB);
    w1e[i] = bfc(w1[o * 576 + cc * 9 + kk] * s);
    return;
  }
  i -= 64 * 576;
  if (i < 64 * 576) {
    int o = i / 576, r = i - o * 576, kk = r >> 6, c = r & 63;
    float s = g2[o] * rsqrtf(v2[o] + EPSB);
    w2e[i] = bfc(w2[(o * 64 + c) * 9 + kk] * s);
    return;
  }
  i -= 64 * 576;
  if (i < 64) {
    float s = g1[i] * rsqrtf(v1[i] + EPSB);
    bias1[i] = b1[i] * s + be1[i] - m1[i] * s;
  } else if (i < 128) {
    int o = i - 64;
    float s = g2[o] * rsqrtf(v2[o] + EPSB);
    bias2[o] = b2[o] * s + be2[o] - m2[o] * s;
  }
}

// ---------------- K12: 128-px tile; A(c+1) loaded after GEMM2(c), before bar2 ----------------
// Single aF live range (no rotation), crosses exactly ONE barrier (a2f pattern).
__global__ __launch_bounds__(512, 4) void k12_kernel(
    const float* __restrict__ new_xyz, const float* __restrict__ feature,
    const unsigned short* __restrict__ wAe, const unsigned short* __restrict__ w1e,
    const float* __restrict__ bias1, unsigned short* __restrict__ h1g)
{
  // LDS 77824 B: B1 [128][168] @0 (43008) | B2 [128][136] @43008 (34816)
  // xyzb [23][136] (6256 B) + lut[160] alias B2.
  __shared__ __align__(16) unsigned char smem[77824];
  unsigned short* B1p  = (unsigned short*)smem;
  unsigned short* B2p  = (unsigned short*)(smem + 43008);
  unsigned short* xyzb = B2p;
  int* lut             = (int*)(smem + 43008 + 6256);

  const int bx = blockIdx.x;
  const int x0 = bx * 128;
  const int y  = blockIdx.y;
  const int n  = blockIdx.z;
  const int tid = threadIdx.x;
  const int lane = tid & 63;
  const int wv = tid >> 6;
  const int r16 = lane & 15;
  const int kq = (lane >> 4) & 3;
  const int l32 = lane & 31;
  const int hi = lane >> 5;
  const int wrow = wv & 3, wcol = wv >> 2;
  const int wh = wrow >> 1;
  const bool xedge = (bx == 0) || (bx == 3);

  // ---- stage new_xyz rows (c,ki) 0..20, width 134 (halo 3) ----
  for (int row = wv; row < 21; row += 8) {
    int c = (row >= 14) ? 2 : (row >= 7 ? 1 : 0);
    int ki = row - c * 7;
    int yy = y + ki - 3;
    bool rowok = (unsigned)yy < 64u;
    unsigned short* dst = xyzb + row * 136;
    if (rowok && !xedge) {
      const float* src = new_xyz + ((n * 3 + c) * 64 + yy) * 512 + (x0 - 3);
      dst[lane] = bfc(src[lane]);
      dst[64 + lane] = bfc(src[64 + lane]);
      if (lane < 6) dst[128 + lane] = bfc(src[128 + lane]);
    } else {
      const float* src = new_xyz + ((n * 3 + c) * 64 + yy) * 512;
#pragma unroll
      for (int seg = 0; seg < 3; ++seg) {
        int xx = lane + seg * 64;
        if (xx < 134) {
          int xg = x0 + xx - 3;
          float v = (rowok && (unsigned)xg < 512u) ? src[xg] : 0.f;
          dst[xx] = bfc(v);
        }
      }
    }
  }
  if (tid < 136) { xyzb[21 * 136 + tid] = 0; xyzb[22 * 136 + tid] = 0x3F80; }
  else if (tid >= 256 && tid < 416) {
    int k = tid - 256;
    int off;
    if (k < 147) { int c = k / 49, rem = k - c * 49, ki = rem / 7, kj = rem - ki * 7; off = (c * 7 + ki) * 136 + kj; }
    else if (k == 147) off = 22 * 136;
    else off = 21 * 136;
    lut[k] = off;
  }
  __syncthreads();   // xyzb + lut ready

  // ---- build im2col B1 ----
  {
    int p = tid >> 2, q = tid & 3;
    unsigned short* brow = B1p + p * 168;
#pragma unroll
    for (int j = 0; j < 10; ++j) {
      int k = (q * 10 + j) * 4;
      int o0 = lut[k], o1 = lut[k + 1], o2 = lut[k + 2], o3 = lut[k + 3];
      uint2 w;
      w.x = (unsigned int)xyzb[o0 + p] | ((unsigned int)xyzb[o1 + p] << 16);
      w.y = (unsigned int)xyzb[o2 + p] | ((unsigned int)xyzb[o3 + p] << 16);
      *(uint2*)(brow + k) = w;
    }
  }

  const int p64 = 64 * wcol;
  const int ccq = (wrow & 1) * 32;
  const unsigned short* Bp1a = B1p + (p64 + l32) * 168 + hi * 8;
  const unsigned short* Bp1b = Bp1a + 32 * 168;

  auto load_aF = [&](int c, bf16x8* dst) {
    int rowb = (c < 4) ? (c * 128 + wrow * 32) : (512 + (wrow & 1) * 32);
    const unsigned short* Ap = wAe + (rowb + l32) * 160 + hi * 8;
#pragma unroll
    for (int j = 0; j < 10; ++j) dst[j] = *(const bf16x8*)(Ap + j * 16);
  };

  // ---- prologue: A(0) into aF (fenced by B1-ready barrier, hides under staging) ----
  bf16x8 aF[10];
  load_aF(0, aF);

  f32x4 acc2[4];
#pragma unroll
  for (int i = 0; i < 4; ++i) acc2[i] = {0.f, 0.f, 0.f, 0.f};

  __syncthreads();   // B1 ready; aF(0) fenced

#pragma unroll
  for (int c = 0; c < 4; ++c) {
    const int kkA = 2 * c + wh;
    const int di = (kkA >= 6) ? 2 : (kkA >= 3 ? 1 : 0);
    const int dj = kkA - 3 * di;

    // ---- GEMM1 chunk c: A from regs, B from LDS ----
    f32x16 acc1a, acc1b;
#pragma unroll
    for (int i = 0; i < 16; ++i) { acc1a[i] = 0.f; acc1b[i] = 0.f; }
#pragma unroll
    for (int j = 0; j < 10; ++j) {
      bf16x8 ba = *(const bf16x8*)(Bp1a + j * 16);
      bf16x8 bb = *(const bf16x8*)(Bp1b + j * 16);
      acc1a = __builtin_amdgcn_mfma_f32_32x32x16_bf16(aF[j], ba, acc1a, 0, 0, 0);
      acc1b = __builtin_amdgcn_mfma_f32_32x32x16_bf16(aF[j], bb, acc1b, 0, 0, 0);
    }

    // ---- gate: fvv loads + sigmoid*feature -> B2 (aF dead here) ----
    {
      const int yy = y + di - 1;
      const bool yok = (unsigned)yy < 64u;
      float fvv[32];
#pragma unroll
      for (int h = 0; h < 2; ++h) {
        const int xg = x0 + p64 + 32 * h + l32 + dj - 1;
        const bool ok = yok && ((unsigned)xg < 512u);
        const float* fbase = feature + (n * 4096 + yy) * 512 + xg;
#pragma unroll
        for (int q = 0; q < 4; ++q) {
          const int c0 = ccq + 8 * q + 4 * hi;
#pragma unroll
          for (int j = 0; j < 4; ++j)
            fvv[16 * h + 4 * q + j] = ok ? fbase[(c0 + j) * 32768] : 0.f;
        }
      }
#pragma unroll
      for (int h = 0; h < 2; ++h) {
        unsigned short* brow2 = B2p + (p64 + 32 * h + l32) * 136 + wrow * 32;
        const f32x16& a1 = h ? acc1b : acc1a;
#pragma unroll
        for (int q = 0; q < 4; ++q) {
          int r0 = 8 * q + 4 * hi;
          float s0 = sigm(a1[4 * q + 0]) * fvv[16 * h + 4 * q + 0];
          float s1 = sigm(a1[4 * q + 1]) * fvv[16 * h + 4 * q + 1];
          float s2 = sigm(a1[4 * q + 2]) * fvv[16 * h + 4 * q + 2];
          float s3 = sigm(a1[4 * q + 3]) * fvv[16 * h + 4 * q + 3];
          uint2 w; w.x = pk2(s0, s1); w.y = pk2(s2, s3);
          *(uint2*)(brow2 + r0) = w;
        }
      }
    }

    // ---- GEMM2 A prefetch (crosses bar1, a2f pattern) ----
    bf16x8 a2f[4];
    const unsigned short* A2p = w1e + (16 * wrow + r16) * 576 + c * 128 + kq * 8;
#pragma unroll
    for (int kst = 0; kst < 4; ++kst) a2f[kst] = *(const bf16x8*)(A2p + kst * 32);

    __syncthreads();   // bar1: B2 chunk visible

    // ---- GEMM2 chunk c ----
#pragma unroll
    for (int kst = 0; kst < 4; ++kst) {
#pragma unroll
      for (int pf = 0; pf < 4; ++pf) {
        bf16x8 b = *(const bf16x8*)(B2p + (p64 + 16 * pf + r16) * 136 + kst * 32 + kq * 8);
        acc2[pf] = __builtin_amdgcn_mfma_f32_16x16x32_bf16(a2f[kst], b, acc2[pf], 0, 0, 0);
      }
    }

    // ---- A(c+1) into aF: old value dead, load crosses ONLY bar2 ----
    load_aF(c + 1, aF);

    __syncthreads();   // bar2: B2 reads drained; aF loads pinned in flight
  }

  // ---- tail chunk: rows 512..575 (kk=8: di=2, dj=2), GEMM1 by wrow<2 ----
  {
    if (wrow < 2) {
      const int yy = y + 1;
      const bool yok = (unsigned)yy < 64u;
      float fvv[32];
#pragma unroll
      for (int h = 0; h < 2; ++h) {
        const int xg = x0 + p64 + 32 * h + l32 + 1;
        const bool ok = yok && ((unsigned)xg < 512u);
        const float* fbase = feature + (n * 4096 + yy) * 512 + xg;
#pragma unroll
        for (int q = 0; q < 4; ++q) {
          const int c0 = ccq + 8 * q + 4 * hi;
#pragma unroll
          for (int j = 0; j < 4; ++j)
            fvv[16 * h + 4 * q + j] = ok ? fbase[(c0 + j) * 32768] : 0.f;
        }
      }
      f32x16 acc1a, acc1b;
#pragma unroll
      for (int i = 0; i < 16; ++i) { acc1a[i] = 0.f; acc1b[i] = 0.f; }
#pragma unroll
      for (int j = 0; j < 10; ++j) {
        bf16x8 ba = *(const bf16x8*)(Bp1a + j * 16);
        bf16x8 bb = *(const bf16x8*)(Bp1b + j * 16);
        acc1a = __builtin_amdgcn_mfma_f32_32x32x16_bf16(aF[j], ba, acc1a, 0, 0, 0);
        acc1b = __builtin_amdgcn_mfma_f32_32x32x16_bf16(aF[j], bb, acc1b, 0, 0, 0);
      }
#pragma unroll
      for (int h = 0; h < 2; ++h) {
        unsigned short* brow2 = B2p + (p64 + 32 * h + l32) * 136 + wrow * 32;
        const f32x16& a1 = h ? acc1b : acc1a;
#pragma unroll
        for (int q = 0; q < 4; ++q) {
          int r0 = 8 * q + 4 * hi;
          float s0 = sigm(a1[4 * q + 0]) * fvv[16 * h + 4 * q + 0];
          float s1 = sigm(a1[4 * q + 1]) * fvv[16 * h + 4 * q + 1];
          float s2 = sigm(a1[4 * q + 2]) * fvv[16 * h + 4 * q + 2];
          float s3 = sigm(a1[4 * q + 3]) * fvv[16 * h + 4 * q + 3];
          uint2 w; w.x = pk2(s0, s1); w.y = pk2(s2, s3);
          *(uint2*)(brow2 + r0) = w;
        }
      }
    }
    bf16x8 a2f[2];
    const unsigned short* A2p = w1e + (16 * wrow + r16) * 576 + 512 + kq * 8;
    a2f[0] = *(const bf16x8*)(A2p);
    a2f[1] = *(const bf16x8*)(A2p + 32);
    __syncthreads();
#pragma unroll
    for (int kst = 0; kst < 2; ++kst) {
#pragma unroll
      for (int pf = 0; pf < 4; ++pf) {
        bf16x8 b = *(const bf16x8*)(B2p + (p64 + 16 * pf + r16) * 136 + kst * 32 + kq * 8);
        acc2[pf] = __builtin_amdgcn_mfma_f32_16x16x32_bf16(a2f[kst], b, acc2[pf], 0, 0, 0);
      }
    }
    __syncthreads();   // B2 reads drained before epilogue writes
  }

  // ---- epilogue: h1 = relu(acc2 + bias1), transpose via B2 ----
  const int ccb = 16 * wrow + 4 * kq;
  float b1v0 = bias1[ccb], b1v1 = bias1[ccb + 1], b1v2 = bias1[ccb + 2], b1v3 = bias1[ccb + 3];
#pragma unroll
  for (int pf = 0; pf < 4; ++pf) {
    int p = p64 + 16 * pf + r16;
    uint2 w;
    w.x = pk2(fmaxf(acc2[pf][0] + b1v0, 0.f), fmaxf(acc2[pf][1] + b1v1, 0.f));
    w.y = pk2(fmaxf(acc2[pf][2] + b1v2, 0.f), fmaxf(acc2[pf][3] + b1v3, 0.f));
    *(uint2*)(B2p + p * 136 + ccb) = w;
  }
  __syncthreads();
  {
    int p = tid >> 2, c0 = (tid & 3) * 16;
    uint4 v0 = *(const uint4*)(B2p + p * 136 + c0);
    uint4 v1 = *(const uint4*)(B2p + p * 136 + c0 + 8);
    unsigned short* dst = h1g + (((n * 64 + y) * 512) + x0 + p) * 64 + c0;
    *(uint4*)dst = v0;
    *(uint4*)(dst + 8) = v1;
  }
}

// ---------------- K3: 3x3 conv 64->64 + BN + ReLU + residual ----------------
__global__ __launch_bounds__(256) void k3_kernel(
    const unsigned short* __restrict__ h1g, const float* __restrict__ feature,
    const unsigned short* __restrict__ w2e, const float* __restrict__ bias2,
    float* __restrict__ out)
{
  __shared__ unsigned short s_h1[3][66][72];

  const int x0 = blockIdx.x * 64;
  const int y  = blockIdx.y;
  const int n  = blockIdx.z;
  const int tid = threadIdx.x;
  const int lane = tid & 63;
  const int wv = tid >> 6;
  const int r16 = lane & 15;
  const int kq = lane >> 4;

  for (int idx = tid; idx < 3 * 66 * 16; idx += 256) {
    int r = idx / (66 * 16), rem = idx - r * 66 * 16, xx = rem >> 4, c0 = (rem & 15) << 2;
    int yy = y + r - 1, xg = x0 + xx - 1;
    uint2 v; v.x = 0u; v.y = 0u;
    if (yy >= 0 && yy < 64 && xg >= 0 && xg < 512)
      v = *(const uint2*)(h1g + (((n * 64 + yy) * 512) + xg) * 64 + c0);
    *(uint2*)(&s_h1[r][xx][c0]) = v;
  }
  __syncthreads();

  f32x4 acc[4];
#pragma unroll
  for (int i = 0; i < 4; ++i) acc[i] = {0.f, 0.f, 0.f, 0.f};

  const unsigned short* Ap = w2e + (16 * wv + r16) * 576 + kq * 8;
#pragma unroll 2
  for (int kst = 0; kst < 18; ++kst) {
    bf16x8 a = *(const bf16x8*)(Ap + kst * 32);
    int kk = kst >> 1, di = kk / 3, dj = kk - di * 3;
    int chalf = (kst & 1) << 5;
#pragma unroll
    for (int pf = 0; pf < 4; ++pf) {
      bf16x8 b = *(const bf16x8*)(&s_h1[di][pf * 16 + r16 + dj][chalf + kq * 8]);
      acc[pf] = __builtin_amdgcn_mfma_f32_16x16x32_bf16(a, b, acc[pf], 0, 0, 0);
    }
  }

#pragma unroll
  for (int pf = 0; pf < 4; ++pf) {
    int p = pf * 16 + r16;
#pragma unroll
    for (int r = 0; r < 4; ++r) {
      int ch = 16 * wv + kq * 4 + r;
      int off = (((n * 64 + ch) * 64) + y) * 512 + x0 + p;
      out[off] = fmaxf(acc[pf][r] + bias2[ch], 0.f) + feature[off];
    }
  }
}

// ---------------- launch ----------------
extern "C" void kernel_launch(void* const* d_in, const int* in_sizes, int n_in,
                              void* d_out, int out_size, void* d_ws, size_t ws_size,
                              hipStream_t stream)
{
  const float* new_xyz = (const float*)d_in[1];
  const float* feature = (const float*)d_in[2];
  const float* w_att = (const float*)d_in[3];
  const float* b_att = (const float*)d_in[4];
  const float* gA  = (const float*)d_in[5];
  const float* beA = (const float*)d_in[6];
  const float* mA  = (const float*)d_in[7];
  const float* vA  = (const float*)d_in[8];
  const float* w1  = (const float*)d_in[9];
  const float* b1  = (const float*)d_in[10];
  const float* g1  = (const float*)d_in[11];
  const float* be1 = (const float*)d_in[12];
  const float* m1  = (const float*)d_in[13];
  const float* v1  = (const float*)d_in[14];
  const float* w2  = (const float*)d_in[15];
  const float* b2  = (const float*)d_in[16];
  const float* g2  = (const float*)d_in[17];
  const float* be2 = (const float*)d_in[18];
  const float* m2  = (const float*)d_in[19];
  const float* v2  = (const float*)d_in[20];

  char* ws = (char*)d_ws;
  unsigned short* wAe = (unsigned short*)(ws);               // 576*160*2 = 184320
  unsigned short* w1e = (unsigned short*)(ws + 184320);      // 73728
  unsigned short* w2e = (unsigned short*)(ws + 258048);      // 73728
  float* bias1 = (float*)(ws + 331776);                      // 256
  float* bias2 = (float*)(ws + 332032);                      // 256
  unsigned short* h1g = (unsigned short*)(ws + 335872);      // 16 MB

  prep_kernel<<<649, 256, 0, stream>>>(w_att, b_att, gA, beA, mA, vA,
                                       w1, b1, g1, be1, m1, v1,
                                       w2, b2, g2, be2, m2, v2,
                                       wAe, w1e, w2e, bias1, bias2);
  k12_kernel<<<dim3(4, 64, 4), 512, 0, stream>>>(new_xyz, feature, wAe, w1e, bias1, h1g);
  k3_kernel<<<dim3(8, 64, 4), 256, 0, stream>>>(h1g, feature, w2e, bias2, (float*)d_out);
}

// Round 17
// 119.809 us; speedup vs baseline: 2.2298x; 2.2298x over previous
//
#include <hip/hip_runtime.h>

#define EPSB 1e-5f

typedef __bf16 bf16x8 __attribute__((ext_vector_type(8)));
typedef float f32x4 __attribute__((ext_vector_type(4)));
typedef float f32x16 __attribute__((ext_vector_type(16)));

__device__ __forceinline__ unsigned short bfc(float v) {
  __bf16 h = (__bf16)v;
  return __builtin_bit_cast(unsigned short, h);
}
__device__ __forceinline__ unsigned int pk2(float a, float b) {
  return (unsigned int)bfc(a) | ((unsigned int)bfc(b) << 16);
}
__device__ __forceinline__ float sigm(float x) {
  float e = __builtin_amdgcn_exp2f(-x * 1.4426950408889634f);
  return __builtin_amdgcn_rcpf(1.0f + e);
}

// ---------------- prep: fold BN into bf16 weights ----------------
// wAe: [576][160] bf16, rows PERMUTED row' = kk*64+cc (o = cc*9+kk); k=147 bias slot
// w1e: [64][576] bf16, k permuted k' = kk*64+cc ; w2e: [64][576] kk-major
__global__ void prep_kernel(
    const float* __restrict__ w_att, const float* __restrict__ b_att,
    const float* __restrict__ gA, const float* __restrict__ beA,
    const float* __restrict__ mA, const float* __restrict__ vA,
    const float* __restrict__ w1, const float* __restrict__ b1,
    const float* __restrict__ g1, const float* __restrict__ be1,
    const float* __restrict__ m1, const float* __restrict__ v1,
    const float* __restrict__ w2, const float* __restrict__ b2,
    const float* __restrict__ g2, const float* __restrict__ be2,
    const float* __restrict__ m2, const float* __restrict__ v2,
    unsigned short* __restrict__ wAe, unsigned short* __restrict__ w1e,
    unsigned short* __restrict__ w2e, float* __restrict__ bias1,
    float* __restrict__ bias2)
{
  int i = blockIdx.x * 256 + threadIdx.x;
  if (i < 576 * 160) {
    int rp = i / 160, k = i - rp * 160;
    int kk = rp >> 6, cc = rp & 63;
    int o = cc * 9 + kk;
    float s = gA[o] * rsqrtf(vA[o] + EPSB);
    float v = 0.f;
    if (k < 147) {
      int c = k / 49, rem = k - c * 49, ki = rem / 7, kj = rem - ki * 7;
      v = w_att[(o * 3 + c) * 49 + ki * 7 + kj] * s;
    } else if (k == 147) {
      v = b_att[o] * s + beA[o] - mA[o] * s;
    }
    wAe[i] = bfc(v);
    return;
  }
  i -= 576 * 160;
  if (i < 64 * 576) {
    int o = i / 576, kp = i - o * 576;
    int kk = kp >> 6, cc = kp & 63;
    float s = g1[o] * rsqrtf(v1[o] + EPSB);
    w1e[i] = bfc(w1[o * 576 + cc * 9 + kk] * s);
    return;
  }
  i -= 64 * 576;
  if (i < 64 * 576) {
    int o = i / 576, r = i - o * 576, kk = r >> 6, c = r & 63;
    float s = g2[o] * rsqrtf(v2[o] + EPSB);
    w2e[i] = bfc(w2[(o * 64 + c) * 9 + kk] * s);
    return;
  }
  i -= 64 * 576;
  if (i < 64) {
    float s = g1[i] * rsqrtf(v1[i] + EPSB);
    bias1[i] = b1[i] * s + be1[i] - m1[i] * s;
  } else if (i < 128) {
    int o = i - 64;
    float s = g2[o] * rsqrtf(v2[o] + EPSB);
    bias2[o] = b2[o] * s + be2[o] - m2[o] * s;
  }
}

// ---------------- K12: 128-px tile; each A-frag feeds 2 MFMAs ----------------
// Block = 128 pixels of one row; 8 waves = 4 rowg x 2 pxg.
// Chunks 0..3 of 128 weight rows + 64-row tail.
__global__ __launch_bounds__(512, 4) void k12_kernel(
    const float* __restrict__ new_xyz, const float* __restrict__ feature,
    const unsigned short* __restrict__ wAe, const unsigned short* __restrict__ w1e,
    const float* __restrict__ bias1, unsigned short* __restrict__ h1g)
{
  // LDS 77824 B: B1 [128][168] @0 (43008) | B2 [128][136] @43008 (34816)
  // xyzb [23][136] (6256 B) + lut[160] alias B2.
  __shared__ __align__(16) unsigned char smem[77824];
  unsigned short* B1p  = (unsigned short*)smem;
  unsigned short* B2p  = (unsigned short*)(smem + 43008);
  unsigned short* xyzb = B2p;
  int* lut             = (int*)(smem + 43008 + 6256);

  const int bx = blockIdx.x;
  const int x0 = bx * 128;
  const int y  = blockIdx.y;
  const int n  = blockIdx.z;
  const int tid = threadIdx.x;
  const int lane = tid & 63;
  const int wv = tid >> 6;
  const int r16 = lane & 15;
  const int kq = (lane >> 4) & 3;
  const int l32 = lane & 31;
  const int hi = lane >> 5;
  const int wrow = wv & 3, wcol = wv >> 2;   // 4 row-groups x 2 px-groups
  const int wh = wrow >> 1;
  const bool xedge = (bx == 0) || (bx == 3);

  // ---- stage new_xyz rows (c,ki) 0..20, width 134 (halo 3) ----
  for (int row = wv; row < 21; row += 8) {
    int c = (row >= 14) ? 2 : (row >= 7 ? 1 : 0);
    int ki = row - c * 7;
    int yy = y + ki - 3;
    bool rowok = (unsigned)yy < 64u;
    unsigned short* dst = xyzb + row * 136;
    if (rowok && !xedge) {
      const float* src = new_xyz + ((n * 3 + c) * 64 + yy) * 512 + (x0 - 3);
      dst[lane] = bfc(src[lane]);
      dst[64 + lane] = bfc(src[64 + lane]);
      if (lane < 6) dst[128 + lane] = bfc(src[128 + lane]);
    } else {
      const float* src = new_xyz + ((n * 3 + c) * 64 + yy) * 512;
#pragma unroll
      for (int seg = 0; seg < 3; ++seg) {
        int xx = lane + seg * 64;
        if (xx < 134) {
          int xg = x0 + xx - 3;
          float v = (rowok && (unsigned)xg < 512u) ? src[xg] : 0.f;
          dst[xx] = bfc(v);
        }
      }
    }
  }
  if (tid < 136) { xyzb[21 * 136 + tid] = 0; xyzb[22 * 136 + tid] = 0x3F80; }
  else if (tid >= 256 && tid < 416) {
    int k = tid - 256;
    int off;
    if (k < 147) { int c = k / 49, rem = k - c * 49, ki = rem / 7, kj = rem - ki * 7; off = (c * 7 + ki) * 136 + kj; }
    else if (k == 147) off = 22 * 136;
    else off = 21 * 136;
    lut[k] = off;
  }
  __syncthreads();   // xyzb + lut ready

  // ---- build im2col B1: thread (p = tid>>2, q = tid&3), 10 uint2 writes ----
  {
    int p = tid >> 2, q = tid & 3;
    unsigned short* brow = B1p + p * 168;
#pragma unroll
    for (int j = 0; j < 10; ++j) {
      int k = (q * 10 + j) * 4;
      int o0 = lut[k], o1 = lut[k + 1], o2 = lut[k + 2], o3 = lut[k + 3];
      uint2 w;
      w.x = (unsigned int)xyzb[o0 + p] | ((unsigned int)xyzb[o1 + p] << 16);
      w.y = (unsigned int)xyzb[o2 + p] | ((unsigned int)xyzb[o3 + p] << 16);
      *(uint2*)(brow + k) = w;
    }
  }
  __syncthreads();   // B1 ready; xyzb/lut dead (B2 free)

  const int p64 = 64 * wcol;
  const int ccq = (wrow & 1) * 32;
  const unsigned short* Bp1a = B1p + (p64 + l32) * 168 + hi * 8;
  const unsigned short* Bp1b = Bp1a + 32 * 168;

  f32x4 acc2[4];
#pragma unroll
  for (int i = 0; i < 4; ++i) acc2[i] = {0.f, 0.f, 0.f, 0.f};

#pragma unroll
  for (int c = 0; c < 4; ++c) {
    const int kkA = 2 * c + wh;
    const int di = (kkA >= 6) ? 2 : (kkA >= 3 ? 1 : 0);
    const int dj = kkA - 3 * di;

    // ---- gate feature prefetch: 32 coalesced dwords (both px halves) ----
    const int yy = y + di - 1;
    const bool yok = (unsigned)yy < 64u;
    float fvv[32];
#pragma unroll
    for (int h = 0; h < 2; ++h) {
      const int xg = x0 + p64 + 32 * h + l32 + dj - 1;
      const bool ok = yok && ((unsigned)xg < 512u);
      const float* fbase = feature + (n * 4096 + yy) * 512 + xg;
#pragma unroll
      for (int q = 0; q < 4; ++q) {
        const int c0 = ccq + 8 * q + 4 * hi;
#pragma unroll
        for (int j = 0; j < 4; ++j)
          fvv[16 * h + 4 * q + j] = ok ? fbase[(c0 + j) * 32768] : 0.f;
      }
    }

    // ---- GEMM1 chunk: rows c*128 + wrow*32, px 64*wcol..+64, K=160 ----
    f32x16 acc1a, acc1b;
#pragma unroll
    for (int i = 0; i < 16; ++i) { acc1a[i] = 0.f; acc1b[i] = 0.f; }
    const unsigned short* Ap = wAe + (c * 128 + wrow * 32 + l32) * 160 + hi * 8;
#pragma unroll
    for (int j = 0; j < 10; ++j) {
      bf16x8 a  = *(const bf16x8*)(Ap + j * 16);
      bf16x8 ba = *(const bf16x8*)(Bp1a + j * 16);
      bf16x8 bb = *(const bf16x8*)(Bp1b + j * 16);
      acc1a = __builtin_amdgcn_mfma_f32_32x32x16_bf16(a, ba, acc1a, 0, 0, 0);
      acc1b = __builtin_amdgcn_mfma_f32_32x32x16_bf16(a, bb, acc1b, 0, 0, 0);
    }

    // ---- GEMM2 A prefetch (cross-barrier registers) ----
    bf16x8 a2f[4];
    const unsigned short* A2p = w1e + (16 * wrow + r16) * 576 + c * 128 + kq * 8;
#pragma unroll
    for (int kst = 0; kst < 4; ++kst) a2f[kst] = *(const bf16x8*)(A2p + kst * 32);

    // ---- gate both halves -> B2 cols wrow*32.. ----
#pragma unroll
    for (int h = 0; h < 2; ++h) {
      unsigned short* brow2 = B2p + (p64 + 32 * h + l32) * 136 + wrow * 32;
      const f32x16& a1 = h ? acc1b : acc1a;
#pragma unroll
      for (int q = 0; q < 4; ++q) {
        int r0 = 8 * q + 4 * hi;
        float s0 = sigm(a1[4 * q + 0]) * fvv[16 * h + 4 * q + 0];
        float s1 = sigm(a1[4 * q + 1]) * fvv[16 * h + 4 * q + 1];
        float s2 = sigm(a1[4 * q + 2]) * fvv[16 * h + 4 * q + 2];
        float s3 = sigm(a1[4 * q + 3]) * fvv[16 * h + 4 * q + 3];
        uint2 w; w.x = pk2(s0, s1); w.y = pk2(s2, s3);
        *(uint2*)(brow2 + r0) = w;
      }
    }
    __syncthreads();   // B2 chunk written

    // ---- GEMM2 partial, K=128: wave = 16 ch x 64 px ----
#pragma unroll
    for (int kst = 0; kst < 4; ++kst) {
#pragma unroll
      for (int pf = 0; pf < 4; ++pf) {
        bf16x8 b = *(const bf16x8*)(B2p + (p64 + 16 * pf + r16) * 136 + kst * 32 + kq * 8);
        acc2[pf] = __builtin_amdgcn_mfma_f32_16x16x32_bf16(a2f[kst], b, acc2[pf], 0, 0, 0);
      }
    }
    __syncthreads();   // B2 reads drained before next gate write
  }

  // ---- tail chunk: rows 512..575 (kk=8: di=2, dj=2), GEMM1 by wrow<2 ----
  {
    if (wrow < 2) {
      const int yy = y + 1;
      const bool yok = (unsigned)yy < 64u;
      float fvv[32];
#pragma unroll
      for (int h = 0; h < 2; ++h) {
        const int xg = x0 + p64 + 32 * h + l32 + 1;
        const bool ok = yok && ((unsigned)xg < 512u);
        const float* fbase = feature + (n * 4096 + yy) * 512 + xg;
#pragma unroll
        for (int q = 0; q < 4; ++q) {
          const int c0 = ccq + 8 * q + 4 * hi;
#pragma unroll
          for (int j = 0; j < 4; ++j)
            fvv[16 * h + 4 * q + j] = ok ? fbase[(c0 + j) * 32768] : 0.f;
        }
      }
      f32x16 acc1a, acc1b;
#pragma unroll
      for (int i = 0; i < 16; ++i) { acc1a[i] = 0.f; acc1b[i] = 0.f; }
      const unsigned short* Ap = wAe + (512 + wrow * 32 + l32) * 160 + hi * 8;
#pragma unroll
      for (int j = 0; j < 10; ++j) {
        bf16x8 a  = *(const bf16x8*)(Ap + j * 16);
        bf16x8 ba = *(const bf16x8*)(Bp1a + j * 16);
        bf16x8 bb = *(const bf16x8*)(Bp1b + j * 16);
        acc1a = __builtin_amdgcn_mfma_f32_32x32x16_bf16(a, ba, acc1a, 0, 0, 0);
        acc1b = __builtin_amdgcn_mfma_f32_32x32x16_bf16(a, bb, acc1b, 0, 0, 0);
      }
#pragma unroll
      for (int h = 0; h < 2; ++h) {
        unsigned short* brow2 = B2p + (p64 + 32 * h + l32) * 136 + wrow * 32;
        const f32x16& a1 = h ? acc1b : acc1a;
#pragma unroll
        for (int q = 0; q < 4; ++q) {
          int r0 = 8 * q + 4 * hi;
          float s0 = sigm(a1[4 * q + 0]) * fvv[16 * h + 4 * q + 0];
          float s1 = sigm(a1[4 * q + 1]) * fvv[16 * h + 4 * q + 1];
          float s2 = sigm(a1[4 * q + 2]) * fvv[16 * h + 4 * q + 2];
          float s3 = sigm(a1[4 * q + 3]) * fvv[16 * h + 4 * q + 3];
          uint2 w; w.x = pk2(s0, s1); w.y = pk2(s2, s3);
          *(uint2*)(brow2 + r0) = w;
        }
      }
    }
    bf16x8 a2f[2];
    const unsigned short* A2p = w1e + (16 * wrow + r16) * 576 + 512 + kq * 8;
    a2f[0] = *(const bf16x8*)(A2p);
    a2f[1] = *(const bf16x8*)(A2p + 32);
    __syncthreads();
#pragma unroll
    for (int kst = 0; kst < 2; ++kst) {
#pragma unroll
      for (int pf = 0; pf < 4; ++pf) {
        bf16x8 b = *(const bf16x8*)(B2p + (p64 + 16 * pf + r16) * 136 + kst * 32 + kq * 8);
        acc2[pf] = __builtin_amdgcn_mfma_f32_16x16x32_bf16(a2f[kst], b, acc2[pf], 0, 0, 0);
      }
    }
    __syncthreads();   // B2 reads drained before epilogue writes
  }

  // ---- epilogue: h1 = relu(acc2 + bias1), transpose via B2 ----
  const int ccb = 16 * wrow + 4 * kq;
  float b1v0 = bias1[ccb], b1v1 = bias1[ccb + 1], b1v2 = bias1[ccb + 2], b1v3 = bias1[ccb + 3];
#pragma unroll
  for (int pf = 0; pf < 4; ++pf) {
    int p = p64 + 16 * pf + r16;
    uint2 w;
    w.x = pk2(fmaxf(acc2[pf][0] + b1v0, 0.f), fmaxf(acc2[pf][1] + b1v1, 0.f));
    w.y = pk2(fmaxf(acc2[pf][2] + b1v2, 0.f), fmaxf(acc2[pf][3] + b1v3, 0.f));
    *(uint2*)(B2p + p * 136 + ccb) = w;
  }
  __syncthreads();
  {
    int p = tid >> 2, c0 = (tid & 3) * 16;
    uint4 v0 = *(const uint4*)(B2p + p * 136 + c0);
    uint4 v1 = *(const uint4*)(B2p + p * 136 + c0 + 8);
    unsigned short* dst = h1g + (((n * 64 + y) * 512) + x0 + p) * 64 + c0;
    *(uint4*)dst = v0;
    *(uint4*)(dst + 8) = v1;
  }
}

// ---------------- K3: 3x3 conv 64->64 + BN + ReLU + residual ----------------
__global__ __launch_bounds__(256) void k3_kernel(
    const unsigned short* __restrict__ h1g, const float* __restrict__ feature,
    const unsigned short* __restrict__ w2e, const float* __restrict__ bias2,
    float* __restrict__ out)
{
  __shared__ unsigned short s_h1[3][66][72];

  const int x0 = blockIdx.x * 64;
  const int y  = blockIdx.y;
  const int n  = blockIdx.z;
  const int tid = threadIdx.x;
  const int lane = tid & 63;
  const int wv = tid >> 6;
  const int r16 = lane & 15;
  const int kq = lane >> 4;

  for (int idx = tid; idx < 3 * 66 * 16; idx += 256) {
    int r = idx / (66 * 16), rem = idx - r * 66 * 16, xx = rem >> 4, c0 = (rem & 15) << 2;
    int yy = y + r - 1, xg = x0 + xx - 1;
    uint2 v; v.x = 0u; v.y = 0u;
    if (yy >= 0 && yy < 64 && xg >= 0 && xg < 512)
      v = *(const uint2*)(h1g + (((n * 64 + yy) * 512) + xg) * 64 + c0);
    *(uint2*)(&s_h1[r][xx][c0]) = v;
  }
  __syncthreads();

  f32x4 acc[4];
#pragma unroll
  for (int i = 0; i < 4; ++i) acc[i] = {0.f, 0.f, 0.f, 0.f};

  const unsigned short* Ap = w2e + (16 * wv + r16) * 576 + kq * 8;
#pragma unroll 2
  for (int kst = 0; kst < 18; ++kst) {
    bf16x8 a = *(const bf16x8*)(Ap + kst * 32);
    int kk = kst >> 1, di = kk / 3, dj = kk - di * 3;
    int chalf = (kst & 1) << 5;
#pragma unroll
    for (int pf = 0; pf < 4; ++pf) {
      bf16x8 b = *(const bf16x8*)(&s_h1[di][pf * 16 + r16 + dj][chalf + kq * 8]);
      acc[pf] = __builtin_amdgcn_mfma_f32_16x16x32_bf16(a, b, acc[pf], 0, 0, 0);
    }
  }

#pragma unroll
  for (int pf = 0; pf < 4; ++pf) {
    int p = pf * 16 + r16;
#pragma unroll
    for (int r = 0; r < 4; ++r) {
      int ch = 16 * wv + kq * 4 + r;
      int off = (((n * 64 + ch) * 64) + y) * 512 + x0 + p;
      out[off] = fmaxf(acc[pf][r] + bias2[ch], 0.f) + feature[off];
    }
  }
}

// ---------------- launch ----------------
extern "C" void kernel_launch(void* const* d_in, const int* in_sizes, int n_in,
                              void* d_out, int out_size, void* d_ws, size_t ws_size,
                              hipStream_t stream)
{
  const float* new_xyz = (const float*)d_in[1];
  const float* feature = (const float*)d_in[2];
  const float* w_att = (const float*)d_in[3];
  const float* b_att = (const float*)d_in[4];
  const float* gA  = (const float*)d_in[5];
  const float* beA = (const float*)d_in[6];
  const float* mA  = (const float*)d_in[7];
  const float* vA  = (const float*)d_in[8];
  const float* w1  = (const float*)d_in[9];
  const float* b1  = (const float*)d_in[10];
  const float* g1  = (const float*)d_in[11];
  const float* be1 = (const float*)d_in[12];
  const float* m1  = (const float*)d_in[13];
  const float* v1  = (const float*)d_in[14];
  const float* w2  = (const float*)d_in[15];
  const float* b2  = (const float*)d_in[16];
  const float* g2  = (const float*)d_in[17];
  const float* be2 = (const float*)d_in[18];
  const float* m2  = (const float*)d_in[19];
  const float* v2  = (const float*)d_in[20];

  char* ws = (char*)d_ws;
  unsigned short* wAe = (unsigned short*)(ws);               // 576*160*2 = 184320
  unsigned short* w1e = (unsigned short*)(ws + 184320);      // 73728
  unsigned short* w2e = (unsigned short*)(ws + 258048);      // 73728
  float* bias1 = (float*)(ws + 331776);                      // 256
  float* bias2 = (float*)(ws + 332032);                      // 256
  unsigned short* h1g = (unsigned short*)(ws + 335872);      // 16 MB

  prep_kernel<<<649, 256, 0, stream>>>(w_att, b_att, gA, beA, mA, vA,
                                       w1, b1, g1, be1, m1, v1,
                                       w2, b2, g2, be2, m2, v2,
                                       wAe, w1e, w2e, bias1, bias2);
  k12_kernel<<<dim3(4, 64, 4), 512, 0, stream>>>(new_xyz, feature, wAe, w1e, bias1, h1g);
  k3_kernel<<<dim3(8, 64, 4), 256, 0, stream>>>(h1g, feature, w2e, bias2, (float*)d_out);
}